// Round 11
// baseline (332.816 us; speedup 1.0000x reference)
//
#include <hip/hip_runtime.h>

typedef unsigned int uint;
typedef unsigned short ushort;
typedef __attribute__((ext_vector_type(8))) short short8;
typedef __attribute__((ext_vector_type(4))) float f32x4;
typedef __attribute__((ext_vector_type(4))) uint uint4w;

#define T_LEN 32768
#define EMB 300
#define HID 256
#define NCOLS 4096

__device__ __forceinline__ ushort f2bf(float f) {
  uint u = __float_as_uint(f);
  return (ushort)((u + 0x7fffu + ((u >> 16) & 1u)) >> 16);
}
__device__ __forceinline__ float bf2f(ushort u) {
  return __uint_as_float(((uint)u) << 16);
}
__device__ __forceinline__ float sigm(float x) { return 1.f / (1.f + __expf(-x)); }
__device__ __forceinline__ float tanh_(float x) { return 2.f / (1.f + __expf(-2.f * x)) - 1.f; }

__device__ __forceinline__ void gload_lds16(const void* g, void* l) {
  __builtin_amdgcn_global_load_lds((const __attribute__((address_space(1))) void*)g,
                                   (__attribute__((address_space(3))) void*)l, 16, 0, 0);
}

// ---------------- prep: bf16 conversions + embedding gather ----------------
// Whh3 layout (per-wave contiguous slices):
//   Whh3[d][s(16)][w(8)] = 4 KB block, inner [c(4)][gi(2)][q(2)][ln(16)][e(8)]
//   element = whh_d[gp*512 + gi*256 + w*32 + q*16 + ln][ks*32 + c*8 + e], s = ks*2+gp
__global__ void prep_kernel(const float* __restrict__ emb,
                            const float* __restrict__ wihf, const float* __restrict__ whhf,
                            const float* __restrict__ bihf, const float* __restrict__ bhhf,
                            const float* __restrict__ wihb, const float* __restrict__ whhb,
                            const float* __restrict__ bihb, const float* __restrict__ bhhb,
                            const int* __restrict__ seq,
                            ushort* __restrict__ X, ushort* __restrict__ Wih,
                            ushort* __restrict__ Whh3, float* __restrict__ bias) {
  const int NX = T_LEN * 40;
  const int NWIH = 2048 * 40;
  const int NWHH = 2048 * 32;
  const int NB = 2048;
  const int total = NX + NWIH + NWHH + NB;
  for (int t = blockIdx.x * blockDim.x + threadIdx.x; t < total; t += gridDim.x * blockDim.x) {
    if (t < NX) {
      int r = t / 40, k8 = t % 40, k = k8 * 8;
      int col = r >> 3, j = r & 7;
      int tok = (col == 0) ? j : (col * 8 - 1 + j);
      const float* src = emb + (long)seq[tok] * EMB + k;
      alignas(16) ushort tmp[8];
#pragma unroll
      for (int i = 0; i < 8; ++i) tmp[i] = (k + i < EMB) ? f2bf(src[i]) : (ushort)0;
      *(uint4w*)(X + (long)r * 320 + k) = *(const uint4w*)tmp;
    } else if (t < NX + NWIH) {
      int t2 = t - NX;
      int n = t2 / 40, k8 = t2 % 40, k = k8 * 8;
      const float* src = ((n < 1024) ? wihf : wihb) + (long)(n & 1023) * EMB + k;
      alignas(16) ushort tmp[8];
#pragma unroll
      for (int i = 0; i < 8; ++i) tmp[i] = (k + i < EMB) ? f2bf(src[i]) : (ushort)0;
      *(uint4w*)(Wih + (long)n * 320 + k) = *(const uint4w*)tmp;
    } else if (t < NX + NWIH + NWHH) {
      int t3 = t - NX - NWIH;
      int n = t3 / 32, k8 = t3 % 32;
      int dd = n >> 10, rowg = n & 1023;
      int gp = rowg >> 9, gi = (rowg >> 8) & 1, w5 = (rowg >> 5) & 7;
      int qq = (rowg >> 4) & 1, lnn = rowg & 15;
      int ks = k8 >> 2, cc = k8 & 3, s = ks * 2 + gp;
      const float* src = ((dd == 0) ? whhf : whhb) + (long)rowg * HID + k8 * 8;
      alignas(16) ushort tmp[8];
#pragma unroll
      for (int i = 0; i < 8; ++i) tmp[i] = f2bf(src[i]);
      long didx = (((long)(dd * 16 + s)) * 8 + w5) * 2048 + cc * 512 + gi * 256 + qq * 128 + lnn * 8;
      *(uint4w*)(Whh3 + didx) = *(const uint4w*)tmp;
    } else {
      int n = t - NX - NWIH - NWHH;
      bias[n] = (n < 1024) ? (bihf[n] + bhhf[n]) : (bihb[n - 1024] + bhhb[n - 1024]);
    }
  }
}

// ---------------- K1: xg = X @ Wih^T + bias  (M=32768,K=320,N=2048) ----------------
__global__ void gemm_xg_kernel(const ushort* __restrict__ X, const ushort* __restrict__ Wih,
                               const float* __restrict__ bias, ushort* __restrict__ xg) {
  __shared__ ushort a_lds[2][128 * 32];
  const int tid = threadIdx.x;
  const int lane = tid & 63, w = tid >> 6;
  const int wr = w >> 1, wc = w & 1;
  const int qrow = lane >> 4, ln = lane & 15;
  const int m0 = blockIdx.x * 128, n0 = blockIdx.y * 128;

  auto stage = [&](int buf, int kt) {
#pragma unroll
    for (int q = 0; q < 2; ++q) {
      int byteoff = w * 2048 + q * 1024 + lane * 16;
      int row = byteoff >> 6, koff = byteoff & 63;
      const char* src = (const char*)X + (long)(m0 + row) * 640 + kt * 64 + koff;
      void* dst = (char*)&a_lds[buf][0] + w * 2048 + q * 1024;
      gload_lds16(src, dst);
    }
  };

  const ushort* wb = Wih + (long)(n0 + wc * 64 + ln) * 320 + qrow * 8;
  auto loadB = [&](short8 (&dst)[4], int kt) {
#pragma unroll
    for (int nt = 0; nt < 4; ++nt)
      dst[nt] = *(const short8*)(wb + nt * 16 * 320 + kt * 32);
  };

  const f32x4 fzero = {0.f, 0.f, 0.f, 0.f};
  f32x4 acc[4][4];
#pragma unroll
  for (int i = 0; i < 4; ++i)
#pragma unroll
    for (int jj = 0; jj < 4; ++jj) acc[i][jj] = fzero;

  auto gemmK = [&](short8 (&b)[4], int buf) {
    short8 a[4];
#pragma unroll
    for (int rt = 0; rt < 4; ++rt)
      a[rt] = *(const short8*)&a_lds[buf][(wr * 64 + rt * 16 + ln) * 32 + qrow * 8];
#pragma unroll
    for (int rt = 0; rt < 4; ++rt)
#pragma unroll
      for (int nt = 0; nt < 4; ++nt)
        acc[rt][nt] = __builtin_amdgcn_mfma_f32_16x16x32_bf16(a[rt], b[nt], acc[rt][nt], 0, 0, 0);
  };

  short8 bA[4], bB[4];
  stage(0, 0);
  loadB(bA, 0);
#pragma unroll 1
  for (int kt2 = 0; kt2 < 5; ++kt2) {
    const int kt = kt2 * 2;
    __syncthreads();
    loadB(bB, kt + 1);
    __builtin_amdgcn_sched_barrier(0);
    if (kt < 9) stage(1, kt + 1);
    __builtin_amdgcn_sched_barrier(0);
    gemmK(bA, 0);
    __syncthreads();
    if (kt2 < 4) loadB(bA, kt + 2);
    __builtin_amdgcn_sched_barrier(0);
    if (kt + 2 < 10) stage(0, kt + 2);
    __builtin_amdgcn_sched_barrier(0);
    gemmK(bB, 1);
  }

  ushort* sbuf = &a_lds[0][0];
  float bv[4];
#pragma unroll
  for (int nt = 0; nt < 4; ++nt) bv[nt] = bias[n0 + wc * 64 + nt * 16 + ln];
#pragma unroll
  for (int R = 0; R < 4; ++R) {
    __syncthreads();
#pragma unroll
    for (int nt = 0; nt < 4; ++nt)
#pragma unroll
      for (int r = 0; r < 4; ++r)
        sbuf[(wr * 16 + qrow * 4 + r) * 128 + wc * 64 + nt * 16 + ln] = f2bf(acc[R][nt][r] + bv[nt]);
    __syncthreads();
#pragma unroll
    for (int p = 0; p < 2; ++p) {
      int row = p * 16 + (tid >> 4);
      int c0 = (tid & 15) * 8;
      uint4w v = *(uint4w*)&sbuf[row * 128 + c0];
      *(uint4w*)&xg[(long)(m0 + (row >> 4) * 64 + R * 16 + (row & 15)) * 2048 + n0 + c0] = v;
    }
  }
}

// ---------------- K2: fused masked LSTM, PER-WAVE autonomous B staging ----------------
// grid 256 = {d} x {cg}; 512 threads (8 waves). Each wave streams ITS 4 KB share of
// each 32-k/gate-pair slice into a private 4-slot LDS ring via global_load_lds,
// ordered by its own vmcnt only. ZERO barriers inside the GEMM (2/step total).
__global__ __launch_bounds__(512) void lstm_kernel(const ushort* __restrict__ xg,
                                                   const ushort* __restrict__ Whh3,
                                                   float* __restrict__ out) {
  __shared__ ushort h_lds[32][264];
  __shared__ alignas(16) char b_lds[8][4][4096];   // [wave][slot][4KB], 128 KB
  const int tid = threadIdx.x;
  const int lane = tid & 63, w = tid >> 6;
  const int qrow = lane >> 4, ln = lane & 15;
  const int bid = blockIdx.x;
  const int d = bid >> 7, cg = bid & 127;

  const char* wsrc = (const char*)Whh3 + (((long)(d * 16) * 8 + w) << 12);  // + s*32768
  char* wdst = &b_lds[w][0][0];

  auto stageB = [&](int s, int slot) {
    const char* src = wsrc + ((long)s << 15) + lane * 16;
    char* dst = wdst + slot * 4096;
#pragma unroll
    for (int q2 = 0; q2 < 4; ++q2) gload_lds16(src + q2 * 1024, dst + q2 * 1024);
  };

  float c_st[2][2][4], h_st[2][2][4];
#pragma unroll
  for (int rt = 0; rt < 2; ++rt)
#pragma unroll
    for (int q = 0; q < 2; ++q)
#pragma unroll
      for (int r = 0; r < 4; ++r) { c_st[rt][q][r] = 0.f; h_st[rt][q][r] = 0.f; }

  const f32x4 fzero = {0.f, 0.f, 0.f, 0.f};

#pragma unroll 1
  for (int it = 0; it < 8; ++it) {
    const int j = d ? (7 - it) : it;
    // step-top barrier: h_lds from previous cell visible
    asm volatile("s_waitcnt lgkmcnt(0)" ::: "memory");
    __builtin_amdgcn_s_barrier();
    asm volatile("" ::: "memory");

    f32x4 acc[4][2][2];
#pragma unroll
    for (int g = 0; g < 4; ++g)
#pragma unroll
      for (int q = 0; q < 2; ++q)
#pragma unroll
        for (int rt = 0; rt < 2; ++rt) acc[g][q][rt] = fzero;

    if (it > 0) {  // h==0 at it==0, skip GEMM
#pragma unroll
      for (int ks = 0; ks < 8; ++ks) {
        short8 a0 = *(const short8*)&h_lds[ln][ks * 32 + qrow * 8];
        short8 a1 = *(const short8*)&h_lds[16 + ln][ks * 32 + qrow * 8];
#pragma unroll
        for (int gp = 0; gp < 2; ++gp) {
          const int p = ks * 2 + gp;
          if (p <= 13)      { asm volatile("s_waitcnt vmcnt(8)" ::: "memory"); }
          else if (p == 14) { asm volatile("s_waitcnt vmcnt(4)" ::: "memory"); }
          else              { asm volatile("s_waitcnt vmcnt(0)" ::: "memory"); }
          if (p <= 12) stageB(p + 3, (p + 3) & 3);
          const char* bb = wdst + (p & 3) * 4096 + qrow * 1024;
#pragma unroll
          for (int gi = 0; gi < 2; ++gi)
#pragma unroll
            for (int q = 0; q < 2; ++q) {
              short8 b = *(const short8*)(bb + gi * 512 + q * 256 + ln * 16);
              const int g = gp * 2 + gi;
              acc[g][q][0] = __builtin_amdgcn_mfma_f32_16x16x32_bf16(a0, b, acc[g][q][0], 0, 0, 0);
              acc[g][q][1] = __builtin_amdgcn_mfma_f32_16x16x32_bf16(a1, b, acc[g][q][1], 0, 0, 0);
            }
        }
      }
    }

    // prefetch next step's first 3 slices (lands during cell phase)
    if (it < 7) { stageB(0, 0); stageB(1, 1); stageB(2, 2); }

    // per-lane xg loads for this step
    const ushort* xgb = xg + (long)(cg * 256 + j) * 2048 + qrow * 65536 + d * 1024 + w * 32 + ln;
    ushort xv[2][2][4][4];
#pragma unroll
    for (int rt = 0; rt < 2; ++rt)
#pragma unroll
      for (int q = 0; q < 2; ++q)
#pragma unroll
        for (int r = 0; r < 4; ++r)
#pragma unroll
          for (int g = 0; g < 4; ++g)
            xv[rt][q][r][g] = xgb[(long)rt * 262144 + r * 16384 + g * 256 + q * 16];

    // GEMM h-reads done before cell overwrites h_lds
    asm volatile("s_waitcnt lgkmcnt(0)" ::: "memory");
    __builtin_amdgcn_s_barrier();
    asm volatile("" ::: "memory");

    const bool mstep = d ? (it == 0) : (it == 7);
#pragma unroll
    for (int rt = 0; rt < 2; ++rt)
#pragma unroll
      for (int q = 0; q < 2; ++q)
#pragma unroll
        for (int r = 0; r < 4; ++r) {
          int cc = rt * 16 + qrow * 4 + r;
          int hid = w * 32 + q * 16 + ln;
          float pi = acc[0][q][rt][r] + bf2f(xv[rt][q][r][0]);
          float pf = acc[1][q][rt][r] + bf2f(xv[rt][q][r][1]);
          float pg = acc[2][q][rt][r] + bf2f(xv[rt][q][r][2]);
          float po = acc[3][q][rt][r] + bf2f(xv[rt][q][r][3]);
          float cn = sigm(pf) * c_st[rt][q][r] + sigm(pi) * tanh_(pg);
          float hn = sigm(po) * tanh_(cn);
          bool skip = mstep && (cg == 0) && (cc == 0);
          if (!skip) { c_st[rt][q][r] = cn; h_st[rt][q][r] = hn; }
          h_lds[cc][hid] = f2bf(h_st[rt][q][r]);
        }
  }

#pragma unroll
  for (int rt = 0; rt < 2; ++rt)
#pragma unroll
    for (int q = 0; q < 2; ++q)
#pragma unroll
      for (int r = 0; r < 4; ++r) {
        int cc = rt * 16 + qrow * 4 + r;
        int hid = w * 32 + q * 16 + ln;
        out[(long)(cg * 32 + cc) * 512 + d * 256 + hid] = h_st[rt][q][r];
      }
}

// ---------------- DIAGNOSTIC probe: pure per-wave gload_lds stream rate ----------------
// Same DMA pattern as lstm's staging, 24 pseudo-steps, no MFMA/cell/barriers.
// Writes checksum into dead scratch (X region). Measures the L2->LDS DMA wall directly.
__global__ __launch_bounds__(512) void probe_stage(const ushort* __restrict__ Whh3,
                                                   float* __restrict__ sink) {
  __shared__ alignas(16) char b_lds[8][4][4096];
  const int tid = threadIdx.x;
  const int lane = tid & 63, w = tid >> 6;
  const int bid = blockIdx.x, d = bid >> 7;
  const char* wsrc = (const char*)Whh3 + (((long)(d * 16) * 8 + w) << 12);
  char* wdst = &b_lds[w][0][0];
  auto stageB = [&](int s, int slot) {
    const char* src = wsrc + ((long)s << 15) + lane * 16;
    char* dst = wdst + slot * 4096;
#pragma unroll
    for (int q2 = 0; q2 < 4; ++q2) gload_lds16(src + q2 * 1024, dst + q2 * 1024);
  };
  float sum = 0.f;
  stageB(0, 0); stageB(1, 1); stageB(2, 2);
#pragma unroll 1
  for (int n = 0; n < 24 * 16; ++n) {
    asm volatile("s_waitcnt vmcnt(8)" ::: "memory");
    const f32x4 v = *(const f32x4*)(wdst + (n & 3) * 4096 + lane * 16);
    sum += v[0] + v[1] + v[2] + v[3];
    stageB((n + 3) & 15, (n + 3) & 3);
  }
  asm volatile("s_waitcnt vmcnt(0)" ::: "memory");
  sum += *(const float*)wdst;
  sink[bid * 512 + tid] = sum;
}

extern "C" void kernel_launch(void* const* d_in, const int* in_sizes, int n_in,
                              void* d_out, int out_size, void* d_ws, size_t ws_size,
                              hipStream_t stream) {
  const float* emb  = (const float*)d_in[0];
  const float* wihf = (const float*)d_in[1];
  const float* whhf = (const float*)d_in[2];
  const float* bihf = (const float*)d_in[3];
  const float* bhhf = (const float*)d_in[4];
  const float* wihb = (const float*)d_in[5];
  const float* whhb = (const float*)d_in[6];
  const float* bihb = (const float*)d_in[7];
  const float* bhhb = (const float*)d_in[8];
  const int*   seq  = (const int*)d_in[9];
  float* out = (float*)d_out;

  char* ws = (char*)d_ws;
  // ws layout (bytes): xg 134217728 | X 20971520 | Wih 1310720 | Whh3 1048576 | bias 8192
  ushort* xg   = (ushort*)(ws);
  ushort* X    = (ushort*)(ws + 134217728);
  ushort* Wih  = (ushort*)(ws + 155189248);
  ushort* Whh3 = (ushort*)(ws + 156499968);
  float*  bias = (float*)(ws + 157548544);

  prep_kernel<<<dim3(1024), dim3(256), 0, stream>>>(emb, wihf, whhf, bihf, bhhf,
                                                    wihb, whhb, bihb, bhhb, seq,
                                                    X, Wih, Whh3, bias);
  gemm_xg_kernel<<<dim3(256, 16), dim3(256), 0, stream>>>(X, Wih, bias, xg);
  lstm_kernel<<<dim3(256), dim3(512), 0, stream>>>(xg, Whh3, out);
  probe_stage<<<dim3(256), dim3(512), 0, stream>>>(Whh3, (float*)X);  // diagnostic, X is dead
}

// Round 12
// 241.384 us; speedup vs baseline: 1.3788x; 1.3788x over previous
//
#include <hip/hip_runtime.h>

typedef unsigned int uint;
typedef unsigned short ushort;
typedef __attribute__((ext_vector_type(8))) short short8;
typedef __attribute__((ext_vector_type(4))) float f32x4;
typedef __attribute__((ext_vector_type(4))) uint uint4w;

#define T_LEN 32768
#define EMB 300
#define HID 256
#define NCOLS 4096

__device__ __forceinline__ ushort f2bf(float f) {
  uint u = __float_as_uint(f);
  return (ushort)((u + 0x7fffu + ((u >> 16) & 1u)) >> 16);
}
__device__ __forceinline__ float bf2f(ushort u) {
  return __uint_as_float(((uint)u) << 16);
}
__device__ __forceinline__ float sigm(float x) { return 1.f / (1.f + __expf(-x)); }
__device__ __forceinline__ float tanh_(float x) { return 2.f / (1.f + __expf(-2.f * x)) - 1.f; }

__device__ __forceinline__ void gload_lds16(const void* g, void* l) {
  __builtin_amdgcn_global_load_lds((const __attribute__((address_space(1))) void*)g,
                                   (__attribute__((address_space(3))) void*)l, 16, 0, 0);
}

// ---------------- prep: bf16 conversions + embedding gather ----------------
// Whh3 layout (per-wave contiguous slices):
//   Whh3[d][s(16)][w(8)] = 4 KB block, inner [c(4)][gi(2)][q(2)][ln(16)][e(8)]
//   element = whh_d[gp*512 + gi*256 + w*32 + q*16 + ln][ks*32 + c*8 + e], s = ks*2+gp
__global__ void prep_kernel(const float* __restrict__ emb,
                            const float* __restrict__ wihf, const float* __restrict__ whhf,
                            const float* __restrict__ bihf, const float* __restrict__ bhhf,
                            const float* __restrict__ wihb, const float* __restrict__ whhb,
                            const float* __restrict__ bihb, const float* __restrict__ bhhb,
                            const int* __restrict__ seq,
                            ushort* __restrict__ X, ushort* __restrict__ Wih,
                            ushort* __restrict__ Whh3, float* __restrict__ bias) {
  const int NX = T_LEN * 40;
  const int NWIH = 2048 * 40;
  const int NWHH = 2048 * 32;
  const int NB = 2048;
  const int total = NX + NWIH + NWHH + NB;
  for (int t = blockIdx.x * blockDim.x + threadIdx.x; t < total; t += gridDim.x * blockDim.x) {
    if (t < NX) {
      int r = t / 40, k8 = t % 40, k = k8 * 8;
      int col = r >> 3, j = r & 7;
      int tok = (col == 0) ? j : (col * 8 - 1 + j);
      const float* src = emb + (long)seq[tok] * EMB + k;
      alignas(16) ushort tmp[8];
#pragma unroll
      for (int i = 0; i < 8; ++i) tmp[i] = (k + i < EMB) ? f2bf(src[i]) : (ushort)0;
      *(uint4w*)(X + (long)r * 320 + k) = *(const uint4w*)tmp;
    } else if (t < NX + NWIH) {
      int t2 = t - NX;
      int n = t2 / 40, k8 = t2 % 40, k = k8 * 8;
      const float* src = ((n < 1024) ? wihf : wihb) + (long)(n & 1023) * EMB + k;
      alignas(16) ushort tmp[8];
#pragma unroll
      for (int i = 0; i < 8; ++i) tmp[i] = (k + i < EMB) ? f2bf(src[i]) : (ushort)0;
      *(uint4w*)(Wih + (long)n * 320 + k) = *(const uint4w*)tmp;
    } else if (t < NX + NWIH + NWHH) {
      int t3 = t - NX - NWIH;
      int n = t3 / 32, k8 = t3 % 32;
      int dd = n >> 10, rowg = n & 1023;
      int gp = rowg >> 9, gi = (rowg >> 8) & 1, w5 = (rowg >> 5) & 7;
      int qq = (rowg >> 4) & 1, lnn = rowg & 15;
      int ks = k8 >> 2, cc = k8 & 3, s = ks * 2 + gp;
      const float* src = ((dd == 0) ? whhf : whhb) + (long)rowg * HID + k8 * 8;
      alignas(16) ushort tmp[8];
#pragma unroll
      for (int i = 0; i < 8; ++i) tmp[i] = f2bf(src[i]);
      long didx = (((long)(dd * 16 + s)) * 8 + w5) * 2048 + cc * 512 + gi * 256 + qq * 128 + lnn * 8;
      *(uint4w*)(Whh3 + didx) = *(const uint4w*)tmp;
    } else {
      int n = t - NX - NWIH - NWHH;
      bias[n] = (n < 1024) ? (bihf[n] + bhhf[n]) : (bihb[n - 1024] + bhhb[n - 1024]);
    }
  }
}

// ---------------- K1: xg = X @ Wih^T + bias  (M=32768,K=320,N=2048) ----------------
__global__ void gemm_xg_kernel(const ushort* __restrict__ X, const ushort* __restrict__ Wih,
                               const float* __restrict__ bias, ushort* __restrict__ xg) {
  __shared__ ushort a_lds[2][128 * 32];
  const int tid = threadIdx.x;
  const int lane = tid & 63, w = tid >> 6;
  const int wr = w >> 1, wc = w & 1;
  const int qrow = lane >> 4, ln = lane & 15;
  const int m0 = blockIdx.x * 128, n0 = blockIdx.y * 128;

  auto stage = [&](int buf, int kt) {
#pragma unroll
    for (int q = 0; q < 2; ++q) {
      int byteoff = w * 2048 + q * 1024 + lane * 16;
      int row = byteoff >> 6, koff = byteoff & 63;
      const char* src = (const char*)X + (long)(m0 + row) * 640 + kt * 64 + koff;
      void* dst = (char*)&a_lds[buf][0] + w * 2048 + q * 1024;
      gload_lds16(src, dst);
    }
  };

  const ushort* wb = Wih + (long)(n0 + wc * 64 + ln) * 320 + qrow * 8;
  auto loadB = [&](short8 (&dst)[4], int kt) {
#pragma unroll
    for (int nt = 0; nt < 4; ++nt)
      dst[nt] = *(const short8*)(wb + nt * 16 * 320 + kt * 32);
  };

  const f32x4 fzero = {0.f, 0.f, 0.f, 0.f};
  f32x4 acc[4][4];
#pragma unroll
  for (int i = 0; i < 4; ++i)
#pragma unroll
    for (int jj = 0; jj < 4; ++jj) acc[i][jj] = fzero;

  auto gemmK = [&](short8 (&b)[4], int buf) {
    short8 a[4];
#pragma unroll
    for (int rt = 0; rt < 4; ++rt)
      a[rt] = *(const short8*)&a_lds[buf][(wr * 64 + rt * 16 + ln) * 32 + qrow * 8];
#pragma unroll
    for (int rt = 0; rt < 4; ++rt)
#pragma unroll
      for (int nt = 0; nt < 4; ++nt)
        acc[rt][nt] = __builtin_amdgcn_mfma_f32_16x16x32_bf16(a[rt], b[nt], acc[rt][nt], 0, 0, 0);
  };

  short8 bA[4], bB[4];
  stage(0, 0);
  loadB(bA, 0);
#pragma unroll 1
  for (int kt2 = 0; kt2 < 5; ++kt2) {
    const int kt = kt2 * 2;
    __syncthreads();
    loadB(bB, kt + 1);
    __builtin_amdgcn_sched_barrier(0);
    if (kt < 9) stage(1, kt + 1);
    __builtin_amdgcn_sched_barrier(0);
    gemmK(bA, 0);
    __syncthreads();
    if (kt2 < 4) loadB(bA, kt + 2);
    __builtin_amdgcn_sched_barrier(0);
    if (kt + 2 < 10) stage(0, kt + 2);
    __builtin_amdgcn_sched_barrier(0);
    gemmK(bB, 1);
  }

  ushort* sbuf = &a_lds[0][0];
  float bv[4];
#pragma unroll
  for (int nt = 0; nt < 4; ++nt) bv[nt] = bias[n0 + wc * 64 + nt * 16 + ln];
#pragma unroll
  for (int R = 0; R < 4; ++R) {
    __syncthreads();
#pragma unroll
    for (int nt = 0; nt < 4; ++nt)
#pragma unroll
      for (int r = 0; r < 4; ++r)
        sbuf[(wr * 16 + qrow * 4 + r) * 128 + wc * 64 + nt * 16 + ln] = f2bf(acc[R][nt][r] + bv[nt]);
    __syncthreads();
#pragma unroll
    for (int p = 0; p < 2; ++p) {
      int row = p * 16 + (tid >> 4);
      int c0 = (tid & 15) * 8;
      uint4w v = *(uint4w*)&sbuf[row * 128 + c0];
      *(uint4w*)&xg[(long)(m0 + (row >> 4) * 64 + R * 16 + (row & 15)) * 2048 + n0 + c0] = v;
    }
  }
}

// ---------------- K2: fused masked LSTM, per-wave staging + operand pipelining ----------------
// grid 256 = {d} x {cg}; 512 threads (8 waves). Per-wave autonomous B staging (4-slot
// ring, vmcnt(4) per phase => slice p+1 landed => one-phase-ahead register prefetch of
// B/A fragments is race-free). lgkmcnt counted waits + sched_barrier pin the pipeline.
__global__ __launch_bounds__(512) void lstm_kernel(const ushort* __restrict__ xg,
                                                   const ushort* __restrict__ Whh3,
                                                   float* __restrict__ out) {
  __shared__ ushort h_lds[32][264];
  __shared__ alignas(16) char b_lds[8][4][4096];   // [wave][slot][4KB], 128 KB
  const int tid = threadIdx.x;
  const int lane = tid & 63, w = tid >> 6;
  const int qrow = lane >> 4, ln = lane & 15;
  const int bid = blockIdx.x;
  const int d = bid >> 7, cg = bid & 127;

  const char* wsrc = (const char*)Whh3 + (((long)(d * 16) * 8 + w) << 12);  // + s*32768
  char* wdst = &b_lds[w][0][0];

  auto stageB = [&](int s, int slot) {
    const char* src = wsrc + ((long)s << 15) + lane * 16;
    char* dst = wdst + slot * 4096;
#pragma unroll
    for (int q2 = 0; q2 < 4; ++q2) gload_lds16(src + q2 * 1024, dst + q2 * 1024);
  };

  float c_st[2][2][4], h_st[2][2][4];
#pragma unroll
  for (int rt = 0; rt < 2; ++rt)
#pragma unroll
    for (int q = 0; q < 2; ++q)
#pragma unroll
      for (int r = 0; r < 4; ++r) { c_st[rt][q][r] = 0.f; h_st[rt][q][r] = 0.f; }

  const f32x4 fzero = {0.f, 0.f, 0.f, 0.f};

#pragma unroll 1
  for (int it = 0; it < 8; ++it) {
    const int j = d ? (7 - it) : it;
    // step-top barrier: h_lds from previous cell visible
    asm volatile("s_waitcnt lgkmcnt(0)" ::: "memory");
    __builtin_amdgcn_s_barrier();
    asm volatile("" ::: "memory");

    f32x4 acc[4][2][2];
#pragma unroll
    for (int g = 0; g < 4; ++g)
#pragma unroll
      for (int q = 0; q < 2; ++q)
#pragma unroll
        for (int rt = 0; rt < 2; ++rt) acc[g][q][rt] = fzero;

    if (it > 0) {  // h==0 at it==0, skip GEMM
      asm volatile("s_waitcnt vmcnt(4)" ::: "memory");  // slices 0,1 landed
      __builtin_amdgcn_sched_barrier(0);
      short8 bbuf[2][4], abuf[2][2];
      {  // bootstrap: slice-0 B frags + ks0 A frags
        const char* bb = wdst + qrow * 1024;
#pragma unroll
        for (int gi = 0; gi < 2; ++gi)
#pragma unroll
          for (int q = 0; q < 2; ++q)
            bbuf[0][gi * 2 + q] = *(const short8*)(bb + gi * 512 + q * 256 + ln * 16);
        abuf[0][0] = *(const short8*)&h_lds[ln][qrow * 8];
        abuf[0][1] = *(const short8*)&h_lds[16 + ln][qrow * 8];
      }
#pragma unroll
      for (int p = 0; p < 16; ++p) {
        const int ks = p >> 1, gp = p & 1;
        // prefetch next-phase operands (slice p+1 guaranteed landed)
        if (p < 15) {
          const char* bb = wdst + ((p + 1) & 3) * 4096 + qrow * 1024;
#pragma unroll
          for (int gi = 0; gi < 2; ++gi)
#pragma unroll
            for (int q = 0; q < 2; ++q)
              bbuf[(p + 1) & 1][gi * 2 + q] = *(const short8*)(bb + gi * 512 + q * 256 + ln * 16);
        }
        if (gp == 1 && ks < 7) {
          abuf[(ks + 1) & 1][0] = *(const short8*)&h_lds[ln][(ks + 1) * 32 + qrow * 8];
          abuf[(ks + 1) & 1][1] = *(const short8*)&h_lds[16 + ln][(ks + 1) * 32 + qrow * 8];
        }
        if (p <= 12) stageB(p + 3, (p + 3) & 3);
        // wait only for the PREVIOUS phase's ds_reads (counted lgkm)
        if (p == 15)                 { asm volatile("s_waitcnt lgkmcnt(0)" ::: "memory"); }
        else if (gp == 1 && ks < 7)  { asm volatile("s_waitcnt lgkmcnt(6)" ::: "memory"); }
        else                         { asm volatile("s_waitcnt lgkmcnt(4)" ::: "memory"); }
        __builtin_amdgcn_sched_barrier(0);
        short8 a0 = abuf[ks & 1][0], a1 = abuf[ks & 1][1];
#pragma unroll
        for (int gi = 0; gi < 2; ++gi)
#pragma unroll
          for (int q = 0; q < 2; ++q) {
            short8 b = bbuf[p & 1][gi * 2 + q];
            const int g = gp * 2 + gi;
            acc[g][q][0] = __builtin_amdgcn_mfma_f32_16x16x32_bf16(a0, b, acc[g][q][0], 0, 0, 0);
            acc[g][q][1] = __builtin_amdgcn_mfma_f32_16x16x32_bf16(a1, b, acc[g][q][1], 0, 0, 0);
          }
        if (p < 15) { asm volatile("s_waitcnt vmcnt(4)" ::: "memory"); }
        __builtin_amdgcn_sched_barrier(0);
      }
    }

    // prefetch next step's first 3 slices (lands during cell phase)
    if (it < 7) { stageB(0, 0); stageB(1, 1); stageB(2, 2); }
    __builtin_amdgcn_sched_barrier(0);

    // per-lane xg loads for this step
    const ushort* xgb = xg + (long)(cg * 256 + j) * 2048 + qrow * 65536 + d * 1024 + w * 32 + ln;
    ushort xv[2][2][4][4];
#pragma unroll
    for (int rt = 0; rt < 2; ++rt)
#pragma unroll
      for (int q = 0; q < 2; ++q)
#pragma unroll
        for (int r = 0; r < 4; ++r)
#pragma unroll
          for (int g = 0; g < 4; ++g)
            xv[rt][q][r][g] = xgb[(long)rt * 262144 + r * 16384 + g * 256 + q * 16];

    // GEMM h-reads done before cell overwrites h_lds
    asm volatile("s_waitcnt lgkmcnt(0)" ::: "memory");
    __builtin_amdgcn_s_barrier();
    asm volatile("" ::: "memory");

    const bool mstep = d ? (it == 0) : (it == 7);
#pragma unroll
    for (int rt = 0; rt < 2; ++rt)
#pragma unroll
      for (int q = 0; q < 2; ++q)
#pragma unroll
        for (int r = 0; r < 4; ++r) {
          int cc = rt * 16 + qrow * 4 + r;
          int hid = w * 32 + q * 16 + ln;
          float pi = acc[0][q][rt][r] + bf2f(xv[rt][q][r][0]);
          float pf = acc[1][q][rt][r] + bf2f(xv[rt][q][r][1]);
          float pg = acc[2][q][rt][r] + bf2f(xv[rt][q][r][2]);
          float po = acc[3][q][rt][r] + bf2f(xv[rt][q][r][3]);
          float cn = sigm(pf) * c_st[rt][q][r] + sigm(pi) * tanh_(pg);
          float hn = sigm(po) * tanh_(cn);
          bool skip = mstep && (cg == 0) && (cc == 0);
          if (!skip) { c_st[rt][q][r] = cn; h_st[rt][q][r] = hn; }
          h_lds[cc][hid] = f2bf(h_st[rt][q][r]);
        }
  }

#pragma unroll
  for (int rt = 0; rt < 2; ++rt)
#pragma unroll
    for (int q = 0; q < 2; ++q)
#pragma unroll
      for (int r = 0; r < 4; ++r) {
        int cc = rt * 16 + qrow * 4 + r;
        int hid = w * 32 + q * 16 + ln;
        out[(long)(cg * 32 + cc) * 512 + d * 256 + hid] = h_st[rt][q][r];
      }
}

extern "C" void kernel_launch(void* const* d_in, const int* in_sizes, int n_in,
                              void* d_out, int out_size, void* d_ws, size_t ws_size,
                              hipStream_t stream) {
  const float* emb  = (const float*)d_in[0];
  const float* wihf = (const float*)d_in[1];
  const float* whhf = (const float*)d_in[2];
  const float* bihf = (const float*)d_in[3];
  const float* bhhf = (const float*)d_in[4];
  const float* wihb = (const float*)d_in[5];
  const float* whhb = (const float*)d_in[6];
  const float* bihb = (const float*)d_in[7];
  const float* bhhb = (const float*)d_in[8];
  const int*   seq  = (const int*)d_in[9];
  float* out = (float*)d_out;

  char* ws = (char*)d_ws;
  // ws layout (bytes): xg 134217728 | X 20971520 | Wih 1310720 | Whh3 1048576 | bias 8192
  ushort* xg   = (ushort*)(ws);
  ushort* X    = (ushort*)(ws + 134217728);
  ushort* Wih  = (ushort*)(ws + 155189248);
  ushort* Whh3 = (ushort*)(ws + 156499968);
  float*  bias = (float*)(ws + 157548544);

  prep_kernel<<<dim3(1024), dim3(256), 0, stream>>>(emb, wihf, whhf, bihf, bhhf,
                                                    wihb, whhb, bihb, bhhb, seq,
                                                    X, Wih, Whh3, bias);
  gemm_xg_kernel<<<dim3(256, 16), dim3(256), 0, stream>>>(X, Wih, bias, xg);
  lstm_kernel<<<dim3(256), dim3(512), 0, stream>>>(xg, Whh3, out);
}

// Round 13
// 239.014 us; speedup vs baseline: 1.3925x; 1.0099x over previous
//
#include <hip/hip_runtime.h>

typedef unsigned int uint;
typedef unsigned short ushort;
typedef __attribute__((ext_vector_type(8))) short short8;
typedef __attribute__((ext_vector_type(4))) float f32x4;
typedef __attribute__((ext_vector_type(4))) uint uint4w;

#define T_LEN 32768
#define EMB 300
#define HID 256
#define NCOLS 4096

__device__ __forceinline__ ushort f2bf(float f) {
  uint u = __float_as_uint(f);
  return (ushort)((u + 0x7fffu + ((u >> 16) & 1u)) >> 16);
}
__device__ __forceinline__ float bf2f(ushort u) {
  return __uint_as_float(((uint)u) << 16);
}
// fast transcendentals: v_exp_f32 (2^x) + v_rcp_f32, ~1ulp — avoids IEEE div sequence
__device__ __forceinline__ float fexp2(float x) {
  float r; asm("v_exp_f32 %0, %1" : "=v"(r) : "v"(x)); return r;
}
__device__ __forceinline__ float frcp(float x) {
  float r; asm("v_rcp_f32 %0, %1" : "=v"(r) : "v"(x)); return r;
}
__device__ __forceinline__ float sigm(float x) {
  return frcp(1.f + fexp2(-1.442695041f * x));
}
__device__ __forceinline__ float tanh_(float x) {
  return 2.f * frcp(1.f + fexp2(-2.885390082f * x)) - 1.f;
}

__device__ __forceinline__ void gload_lds16(const void* g, void* l) {
  __builtin_amdgcn_global_load_lds((const __attribute__((address_space(1))) void*)g,
                                   (__attribute__((address_space(3))) void*)l, 16, 0, 0);
}

// ---------------- prep: bf16 conversions + embedding gather ----------------
// Whh3 layout (per-wave contiguous slices):
//   Whh3[d][s(16)][w(8)] = 4 KB block, inner [c(4)][gi(2)][q(2)][ln(16)][e(8)]
//   element = whh_d[gp*512 + gi*256 + w*32 + q*16 + ln][ks*32 + c*8 + e], s = ks*2+gp
__global__ void prep_kernel(const float* __restrict__ emb,
                            const float* __restrict__ wihf, const float* __restrict__ whhf,
                            const float* __restrict__ bihf, const float* __restrict__ bhhf,
                            const float* __restrict__ wihb, const float* __restrict__ whhb,
                            const float* __restrict__ bihb, const float* __restrict__ bhhb,
                            const int* __restrict__ seq,
                            ushort* __restrict__ X, ushort* __restrict__ Wih,
                            ushort* __restrict__ Whh3, float* __restrict__ bias) {
  const int NX = T_LEN * 40;
  const int NWIH = 2048 * 40;
  const int NWHH = 2048 * 32;
  const int NB = 2048;
  const int total = NX + NWIH + NWHH + NB;
  for (int t = blockIdx.x * blockDim.x + threadIdx.x; t < total; t += gridDim.x * blockDim.x) {
    if (t < NX) {
      int r = t / 40, k8 = t % 40, k = k8 * 8;
      int col = r >> 3, j = r & 7;
      int tok = (col == 0) ? j : (col * 8 - 1 + j);
      const float* src = emb + (long)seq[tok] * EMB + k;
      alignas(16) ushort tmp[8];
#pragma unroll
      for (int i = 0; i < 8; ++i) tmp[i] = (k + i < EMB) ? f2bf(src[i]) : (ushort)0;
      *(uint4w*)(X + (long)r * 320 + k) = *(const uint4w*)tmp;
    } else if (t < NX + NWIH) {
      int t2 = t - NX;
      int n = t2 / 40, k8 = t2 % 40, k = k8 * 8;
      const float* src = ((n < 1024) ? wihf : wihb) + (long)(n & 1023) * EMB + k;
      alignas(16) ushort tmp[8];
#pragma unroll
      for (int i = 0; i < 8; ++i) tmp[i] = (k + i < EMB) ? f2bf(src[i]) : (ushort)0;
      *(uint4w*)(Wih + (long)n * 320 + k) = *(const uint4w*)tmp;
    } else if (t < NX + NWIH + NWHH) {
      int t3 = t - NX - NWIH;
      int n = t3 / 32, k8 = t3 % 32;
      int dd = n >> 10, rowg = n & 1023;
      int gp = rowg >> 9, gi = (rowg >> 8) & 1, w5 = (rowg >> 5) & 7;
      int qq = (rowg >> 4) & 1, lnn = rowg & 15;
      int ks = k8 >> 2, cc = k8 & 3, s = ks * 2 + gp;
      const float* src = ((dd == 0) ? whhf : whhb) + (long)rowg * HID + k8 * 8;
      alignas(16) ushort tmp[8];
#pragma unroll
      for (int i = 0; i < 8; ++i) tmp[i] = f2bf(src[i]);
      long didx = (((long)(dd * 16 + s)) * 8 + w5) * 2048 + cc * 512 + gi * 256 + qq * 128 + lnn * 8;
      *(uint4w*)(Whh3 + didx) = *(const uint4w*)tmp;
    } else {
      int n = t - NX - NWIH - NWHH;
      bias[n] = (n < 1024) ? (bihf[n] + bhhf[n]) : (bihb[n - 1024] + bhhb[n - 1024]);
    }
  }
}

// ---------------- K1: xg = X @ Wih^T + bias  (M=32768,K=320,N=2048) ----------------
// 256x128 tile, 8 waves (512 thr): halves Wih fragment traffic vs 128x128.
__global__ void gemm_xg_kernel(const ushort* __restrict__ X, const ushort* __restrict__ Wih,
                               const float* __restrict__ bias, ushort* __restrict__ xg) {
  __shared__ ushort a_lds[2][256 * 32];   // 2 x 16 KB
  const int tid = threadIdx.x;
  const int lane = tid & 63, w = tid >> 6;
  const int wr = w >> 1, wc = w & 1;      // wr in [0,4), wc in [0,2): wave tile 64x64
  const int qrow = lane >> 4, ln = lane & 15;
  const int m0 = blockIdx.x * 256, n0 = blockIdx.y * 128;

  auto stage = [&](int buf, int kt) {
#pragma unroll
    for (int q = 0; q < 2; ++q) {
      int byteoff = w * 2048 + q * 1024 + lane * 16;   // covers 16 KB = 256 rows x 64 B
      int row = byteoff >> 6, koff = byteoff & 63;
      const char* src = (const char*)X + (long)(m0 + row) * 640 + kt * 64 + koff;
      void* dst = (char*)&a_lds[buf][0] + w * 2048 + q * 1024;
      gload_lds16(src, dst);
    }
  };

  const ushort* wb = Wih + (long)(n0 + wc * 64 + ln) * 320 + qrow * 8;
  auto loadB = [&](short8 (&dst)[4], int kt) {
#pragma unroll
    for (int nt = 0; nt < 4; ++nt)
      dst[nt] = *(const short8*)(wb + nt * 16 * 320 + kt * 32);
  };

  const f32x4 fzero = {0.f, 0.f, 0.f, 0.f};
  f32x4 acc[4][4];
#pragma unroll
  for (int i = 0; i < 4; ++i)
#pragma unroll
    for (int jj = 0; jj < 4; ++jj) acc[i][jj] = fzero;

  auto gemmK = [&](short8 (&b)[4], int buf) {
    short8 a[4];
#pragma unroll
    for (int rt = 0; rt < 4; ++rt)
      a[rt] = *(const short8*)&a_lds[buf][(wr * 64 + rt * 16 + ln) * 32 + qrow * 8];
#pragma unroll
    for (int rt = 0; rt < 4; ++rt)
#pragma unroll
      for (int nt = 0; nt < 4; ++nt)
        acc[rt][nt] = __builtin_amdgcn_mfma_f32_16x16x32_bf16(a[rt], b[nt], acc[rt][nt], 0, 0, 0);
  };

  short8 bA[4], bB[4];
  stage(0, 0);
  loadB(bA, 0);
#pragma unroll 1
  for (int kt2 = 0; kt2 < 5; ++kt2) {
    const int kt = kt2 * 2;
    __syncthreads();
    loadB(bB, kt + 1);
    __builtin_amdgcn_sched_barrier(0);
    if (kt < 9) stage(1, kt + 1);
    __builtin_amdgcn_sched_barrier(0);
    gemmK(bA, 0);
    __syncthreads();
    if (kt2 < 4) loadB(bA, kt + 2);
    __builtin_amdgcn_sched_barrier(0);
    if (kt + 2 < 10) stage(0, kt + 2);
    __builtin_amdgcn_sched_barrier(0);
    gemmK(bB, 1);
  }

  // epilogue: repack through LDS (64x128 chunk = 16 KB spanning both a_lds bufs)
  ushort* sbuf = &a_lds[0][0];
  float bv[4];
#pragma unroll
  for (int nt = 0; nt < 4; ++nt) bv[nt] = bias[n0 + wc * 64 + nt * 16 + ln];
#pragma unroll
  for (int R = 0; R < 4; ++R) {
    __syncthreads();
#pragma unroll
    for (int nt = 0; nt < 4; ++nt)
#pragma unroll
      for (int r = 0; r < 4; ++r)
        sbuf[(wr * 16 + qrow * 4 + r) * 128 + wc * 64 + nt * 16 + ln] = f2bf(acc[R][nt][r] + bv[nt]);
    __syncthreads();
#pragma unroll
    for (int p = 0; p < 2; ++p) {
      int srow = p * 32 + (tid >> 4);          // [0,64)
      int c0 = (tid & 15) * 8;
      uint4w v = *(uint4w*)&sbuf[srow * 128 + c0];
      // global row = m0 + (srow>>4)*64 + R*16 + (srow&15)
      *(uint4w*)&xg[(long)(m0 + (srow >> 4) * 64 + R * 16 + (srow & 15)) * 2048 + n0 + c0] = v;
    }
  }
}

// ---------------- K2: fused masked LSTM, per-wave staging + operand pipelining ----------------
__global__ __launch_bounds__(512) void lstm_kernel(const ushort* __restrict__ xg,
                                                   const ushort* __restrict__ Whh3,
                                                   float* __restrict__ out) {
  __shared__ ushort h_lds[32][264];
  __shared__ alignas(16) char b_lds[8][4][4096];   // [wave][slot][4KB], 128 KB
  const int tid = threadIdx.x;
  const int lane = tid & 63, w = tid >> 6;
  const int qrow = lane >> 4, ln = lane & 15;
  const int bid = blockIdx.x;
  const int d = bid >> 7, cg = bid & 127;

  const char* wsrc = (const char*)Whh3 + (((long)(d * 16) * 8 + w) << 12);  // + s*32768
  char* wdst = &b_lds[w][0][0];

  auto stageB = [&](int s, int slot) {
    const char* src = wsrc + ((long)s << 15) + lane * 16;
    char* dst = wdst + slot * 4096;
#pragma unroll
    for (int q2 = 0; q2 < 4; ++q2) gload_lds16(src + q2 * 1024, dst + q2 * 1024);
  };

  float c_st[2][2][4], h_st[2][2][4];
#pragma unroll
  for (int rt = 0; rt < 2; ++rt)
#pragma unroll
    for (int q = 0; q < 2; ++q)
#pragma unroll
      for (int r = 0; r < 4; ++r) { c_st[rt][q][r] = 0.f; h_st[rt][q][r] = 0.f; }

  const f32x4 fzero = {0.f, 0.f, 0.f, 0.f};

#pragma unroll 1
  for (int it = 0; it < 8; ++it) {
    const int j = d ? (7 - it) : it;
    // step-top barrier: h_lds from previous cell visible
    asm volatile("s_waitcnt lgkmcnt(0)" ::: "memory");
    __builtin_amdgcn_s_barrier();
    asm volatile("" ::: "memory");

    f32x4 acc[4][2][2];
#pragma unroll
    for (int g = 0; g < 4; ++g)
#pragma unroll
      for (int q = 0; q < 2; ++q)
#pragma unroll
        for (int rt = 0; rt < 2; ++rt) acc[g][q][rt] = fzero;

    if (it > 0) {  // h==0 at it==0, skip GEMM
      asm volatile("s_waitcnt vmcnt(4)" ::: "memory");  // slices 0,1 landed
      __builtin_amdgcn_sched_barrier(0);
      short8 bbuf[2][4], abuf[2][2];
      {  // bootstrap: slice-0 B frags + ks0 A frags
        const char* bb = wdst + qrow * 1024;
#pragma unroll
        for (int gi = 0; gi < 2; ++gi)
#pragma unroll
          for (int q = 0; q < 2; ++q)
            bbuf[0][gi * 2 + q] = *(const short8*)(bb + gi * 512 + q * 256 + ln * 16);
        abuf[0][0] = *(const short8*)&h_lds[ln][qrow * 8];
        abuf[0][1] = *(const short8*)&h_lds[16 + ln][qrow * 8];
      }
#pragma unroll
      for (int p = 0; p < 16; ++p) {
        const int ks = p >> 1, gp = p & 1;
        if (p < 15) {
          const char* bb = wdst + ((p + 1) & 3) * 4096 + qrow * 1024;
#pragma unroll
          for (int gi = 0; gi < 2; ++gi)
#pragma unroll
            for (int q = 0; q < 2; ++q)
              bbuf[(p + 1) & 1][gi * 2 + q] = *(const short8*)(bb + gi * 512 + q * 256 + ln * 16);
        }
        if (gp == 1 && ks < 7) {
          abuf[(ks + 1) & 1][0] = *(const short8*)&h_lds[ln][(ks + 1) * 32 + qrow * 8];
          abuf[(ks + 1) & 1][1] = *(const short8*)&h_lds[16 + ln][(ks + 1) * 32 + qrow * 8];
        }
        if (p <= 12) stageB(p + 3, (p + 3) & 3);
        if (p == 15)                 { asm volatile("s_waitcnt lgkmcnt(0)" ::: "memory"); }
        else if (gp == 1 && ks < 7)  { asm volatile("s_waitcnt lgkmcnt(6)" ::: "memory"); }
        else                         { asm volatile("s_waitcnt lgkmcnt(4)" ::: "memory"); }
        __builtin_amdgcn_sched_barrier(0);
        short8 a0 = abuf[ks & 1][0], a1 = abuf[ks & 1][1];
#pragma unroll
        for (int gi = 0; gi < 2; ++gi)
#pragma unroll
          for (int q = 0; q < 2; ++q) {
            short8 b = bbuf[p & 1][gi * 2 + q];
            const int g = gp * 2 + gi;
            acc[g][q][0] = __builtin_amdgcn_mfma_f32_16x16x32_bf16(a0, b, acc[g][q][0], 0, 0, 0);
            acc[g][q][1] = __builtin_amdgcn_mfma_f32_16x16x32_bf16(a1, b, acc[g][q][1], 0, 0, 0);
          }
        if (p < 15) { asm volatile("s_waitcnt vmcnt(4)" ::: "memory"); }
        __builtin_amdgcn_sched_barrier(0);
      }
    }

    // prefetch next step's first 3 slices (lands during cell phase)
    if (it < 7) { stageB(0, 0); stageB(1, 1); stageB(2, 2); }
    __builtin_amdgcn_sched_barrier(0);

    // per-lane xg loads for this step
    const ushort* xgb = xg + (long)(cg * 256 + j) * 2048 + qrow * 65536 + d * 1024 + w * 32 + ln;
    ushort xv[2][2][4][4];
#pragma unroll
    for (int rt = 0; rt < 2; ++rt)
#pragma unroll
      for (int q = 0; q < 2; ++q)
#pragma unroll
        for (int r = 0; r < 4; ++r)
#pragma unroll
          for (int g = 0; g < 4; ++g)
            xv[rt][q][r][g] = xgb[(long)rt * 262144 + r * 16384 + g * 256 + q * 16];

    // GEMM h-reads done before cell overwrites h_lds
    asm volatile("s_waitcnt lgkmcnt(0)" ::: "memory");
    __builtin_amdgcn_s_barrier();
    asm volatile("" ::: "memory");

    const bool mstep = d ? (it == 0) : (it == 7);
#pragma unroll
    for (int rt = 0; rt < 2; ++rt)
#pragma unroll
      for (int q = 0; q < 2; ++q)
#pragma unroll
        for (int r = 0; r < 4; ++r) {
          int cc = rt * 16 + qrow * 4 + r;
          int hid = w * 32 + q * 16 + ln;
          float pi = acc[0][q][rt][r] + bf2f(xv[rt][q][r][0]);
          float pf = acc[1][q][rt][r] + bf2f(xv[rt][q][r][1]);
          float pg = acc[2][q][rt][r] + bf2f(xv[rt][q][r][2]);
          float po = acc[3][q][rt][r] + bf2f(xv[rt][q][r][3]);
          float cn = sigm(pf) * c_st[rt][q][r] + sigm(pi) * tanh_(pg);
          float hn = sigm(po) * tanh_(cn);
          bool skip = mstep && (cg == 0) && (cc == 0);
          if (!skip) { c_st[rt][q][r] = cn; h_st[rt][q][r] = hn; }
          h_lds[cc][hid] = f2bf(h_st[rt][q][r]);
        }
  }

#pragma unroll
  for (int rt = 0; rt < 2; ++rt)
#pragma unroll
    for (int q = 0; q < 2; ++q)
#pragma unroll
      for (int r = 0; r < 4; ++r) {
        int cc = rt * 16 + qrow * 4 + r;
        int hid = w * 32 + q * 16 + ln;
        out[(long)(cg * 32 + cc) * 512 + d * 256 + hid] = h_st[rt][q][r];
      }
}

extern "C" void kernel_launch(void* const* d_in, const int* in_sizes, int n_in,
                              void* d_out, int out_size, void* d_ws, size_t ws_size,
                              hipStream_t stream) {
  const float* emb  = (const float*)d_in[0];
  const float* wihf = (const float*)d_in[1];
  const float* whhf = (const float*)d_in[2];
  const float* bihf = (const float*)d_in[3];
  const float* bhhf = (const float*)d_in[4];
  const float* wihb = (const float*)d_in[5];
  const float* whhb = (const float*)d_in[6];
  const float* bihb = (const float*)d_in[7];
  const float* bhhb = (const float*)d_in[8];
  const int*   seq  = (const int*)d_in[9];
  float* out = (float*)d_out;

  char* ws = (char*)d_ws;
  // ws layout (bytes): xg 134217728 | X 20971520 | Wih 1310720 | Whh3 1048576 | bias 8192
  ushort* xg   = (ushort*)(ws);
  ushort* X    = (ushort*)(ws + 134217728);
  ushort* Wih  = (ushort*)(ws + 155189248);
  ushort* Whh3 = (ushort*)(ws + 156499968);
  float*  bias = (float*)(ws + 157548544);

  prep_kernel<<<dim3(1024), dim3(256), 0, stream>>>(emb, wihf, whhf, bihf, bhhf,
                                                    wihb, whhb, bihb, bhhb, seq,
                                                    X, Wih, Whh3, bias);
  gemm_xg_kernel<<<dim3(128, 16), dim3(512), 0, stream>>>(X, Wih, bias, xg);
  lstm_kernel<<<dim3(256), dim3(512), 0, stream>>>(xg, Whh3, out);
}